// Round 3
// baseline (270.286 us; speedup 1.0000x reference)
//
#include <hip/hip_runtime.h>
#include <hip/hip_bf16.h>

// ContextualConv2d as implicit GEMM on MFMA.
// GEMM view: M = N*H*W = 131072, N = C_OUT = 256, K = CIN*9 = 1152.
// Round 8: RESIDENT-A. r6 (2-phase) and r7 (8-phase+counted-vmcnt) tied at
//          98 us / 31% MfmaUtil => schedule-invariant wall. Shared trait:
//          per-K-tile L2->LDS staging (A re-staged 9x, once per tap).
//          Now: block's full input (6 padded h-rows x 66 x 128ci bf16 = 99 KB)
//          staged ONCE into LDS; K-loop (36 tiles of BK=32) stages only B
//          (triple-buffered 3x16 KB, depth-2 prefetch, vmcnt(2) never 0 until
//          tail, ONE barrier per tile). L2->LDS traffic 1.7x down, in-loop
//          gload_lds insts 4x down, barriers 4x down.
// A swizzle: 16-chunk rows, phys = ((cL&7)^(row&7)) | (cL&8)  (0-conflict).
// B swizzle: 4-chunk rows,  phys = cL ^ ((co>>1)&3)           (8 bank-quads).

#define NN   32
#define CIN  128
#define HH   64
#define WW   64
#define COUT 256
#define CDIM 64
#define HP   66
#define WP   66

#define XP_BYTES  ((size_t)NN*HP*WP*CIN*2)       // 35,684,352
#define WT_BYTES  ((size_t)9*COUT*CIN*2)         //    589,824
#define CTX_BYTES ((size_t)NN*COUT*4)            //     32,768
#define WS_NEEDED (XP_BYTES + WT_BYTES + CTX_BYTES)

typedef __attribute__((ext_vector_type(8))) short short8;   // 8 bf16 = 4 VGPRs
typedef __attribute__((ext_vector_type(4))) float float4v;

__device__ __forceinline__ void async16(const void* g, void* l) {
    __builtin_amdgcn_global_load_lds(
        (const __attribute__((address_space(1))) unsigned int*)g,
        (__attribute__((address_space(3))) unsigned int*)l, 16, 0, 0);
}

#define BAR()      __builtin_amdgcn_s_barrier()
#define SETPRIO(x) __builtin_amdgcn_s_setprio(x)

// ---------------- prep_all: fused zero_halo + prep_x + prep_wc ------------------
__global__ __launch_bounds__(256) void prep_all(
    const float* __restrict__ x, const float* __restrict__ c,
    const float* __restrict__ wgt, const float* __restrict__ cw,
    const float* __restrict__ bias,
    __hip_bfloat16* __restrict__ xP, __hip_bfloat16* __restrict__ wT,
    float* __restrict__ ctx)
{
    __shared__ float tile[CIN][65];
    int bid = blockIdx.x;
    int t   = threadIdx.x;

    if (bid < 2048) {                            // ---- prep_x ----
        int n = bid >> 6;
        int h = bid & 63;
        const float* xb = x + (size_t)n * CIN * HH * WW + (size_t)h * WW;

        int lane16 = t & 15, rgrp = t >> 4;      // 16 lanes x float4 = one 256B row
        #pragma unroll
        for (int i = 0; i < 8; ++i) {
            int ci = rgrp + i * 16;
            float4v v = *(const float4v*)(xb + (size_t)ci * (HH * WW) + lane16 * 4);
            int w0 = lane16 * 4;
            tile[ci][w0]     = v.x;
            tile[ci][w0 + 1] = v.y;
            tile[ci][w0 + 2] = v.z;
            tile[ci][w0 + 3] = v.w;
        }
        __syncthreads();

        int oct = t & 3, w = t >> 2;
        __hip_bfloat16* db = xP + (((size_t)n * HP + (h + 1)) * WP + (w + 1)) * CIN;
        #pragma unroll
        for (int p = 0; p < 4; ++p) {
            int ci0 = p * 32 + oct * 8;
            union { short8 v; __hip_bfloat16 b[8]; } u;
            #pragma unroll
            for (int j = 0; j < 8; ++j)
                u.b[j] = __float2bfloat16(tile[ci0 + j][w]);
            *(short8*)(db + ci0) = u.v;
        }
    } else if (bid < 2568) {                     // ---- zero_halo ----
        int g = (bid - 2048) * 256 + t;          // chunk id, 133120 total
        int n   = g / 4160;
        int rem = g - n * 4160;
        int pi  = rem >> 4;                      // halo position 0..259
        int oct = rem & 15;
        int hh, ww;
        if (pi < 132) { hh = (pi >= 66) ? 65 : 0; ww = pi % 66; }
        else { int p2 = pi - 132; ww = (p2 >= 64) ? 65 : 0; hh = 1 + (p2 & 63); }
        short8 z = {};
        *(short8*)(xP + (((size_t)n * HP + hh) * WP + ww) * CIN + oct * 8) = z;
    } else {                                     // ---- prep_wc ----
        int b2 = bid - 2568;
        if (b2 < 1152) {
            int idx = b2 * 256 + t;              // 294912
            int ci  = idx & 127;
            int co  = (idx >> 7) & 255;
            int tap = idx >> 15;
            wT[idx] = __float2bfloat16(wgt[((size_t)co * CIN + ci) * 9 + tap]);
        } else {
            int idx = (b2 - 1152) * 256 + t;     // 8192
            int co = idx & 255, n = idx >> 8;
            float a = bias[co];
            #pragma unroll 8
            for (int d = 0; d < CDIM; ++d) a += c[n * CDIM + d] * cw[co * CDIM + d];
            ctx[idx] = a;
        }
    }
}

// ---------------- main: implicit-GEMM conv, resident-A, BK=32 ------------------
// grid: 512 blocks = 512 m-tiles (256 positions = 4 h-rows of one n), BN = 256.
// 512 threads = 8 waves (2 m x 4 n); per-wave output 128 pos x 64 co.
// LDS: A = [396 rows (6h x 66w)][128 ci] swizzled, 99 KB (staged ONCE);
//      B = 3 x [256 co][32 k] swizzled, 48 KB (depth-2 prefetch, vmcnt(2)).
// 36 K-tiles (9 taps x 4 kb of 32 ci); per tile: BAR -> stage B(kt+2) ->
// 12 ds_read_b128 -> 32 MFMA (setprio) -> vmcnt(2).
__global__ __launch_bounds__(512) void conv_mfma(
    const __hip_bfloat16* __restrict__ xP,   // [32][66][66][128]
    const __hip_bfloat16* __restrict__ wT,   // [9][256][128]
    const float* __restrict__ ctx,           // [32][256]
    float* __restrict__ out)                 // [32][256][64][64]
{
    __shared__ __align__(16) short A_s[50688];      // 396 x 128, 101,376 B
    __shared__ __align__(16) short B_s[3][8192];    // 3 x 16,384 B

    int bid = blockIdx.x;
    // XCD-bijective swizzle (512 % 8 == 0)
    int mt  = (bid & 7) * 64 + (bid >> 3);
    int n   = mt >> 4;                    // 0..31
    int h0  = (mt & 15) << 2;             // 4 output h-rows per tile

    int tid  = threadIdx.x;
    int lane = tid & 63, wv = tid >> 6;
    int wm = (wv & 1) * 128;              // wave m-offset (positions)
    int wn = (wv >> 1) * 64;              // wave n-offset (co)
    int l15 = lane & 15, lu = lane >> 4;

    // ---- A prologue staging: rows r = hh*66+ww (hh 0..5 padded, ww 0..65),
    // 396 rows x 16 chunks = 6336 chunks of 16B; source octet pre-swizzled.
    const __hip_bfloat16* xPn = xP + (size_t)(n * HP + h0) * WP * CIN;
    #pragma unroll
    for (int rnd = 0; rnd < 13; ++rnd) {
        int g = rnd * 512 + tid;
        if (g < 6336) {
            int r  = g >> 4, cc = g & 15;
            int hh = r / 66;                         // compiler magic-mul
            int ww = r - hh * 66;
            int so = ((cc & 7) ^ (r & 7)) | (cc & 8);
            async16(xPn + ((size_t)hh * WP + ww) * CIN + so * 8, &A_s[g * 8]);
        }
    }

    // ---- B staging precompute: thread covers chunks g0=tid (co 0..127) and
    // g1=512+tid (co 128..255); co = g>>2, cl = g&3, src octet = cl^((co>>1)&3)
    // (same octet for both halves since (co+128)>>1 has same low 2 bits).
    int coS = tid >> 2, clS = tid & 3;
    int soS = clS ^ ((coS >> 1) & 3);
    const __hip_bfloat16* bsrc0 = wT + (size_t)coS * CIN + soS * 8;

    // ---- B prologue: tiles 0 (tap0,kb0) and 1 (tap0,kb1)
    #pragma unroll
    for (int b = 0; b < 2; ++b) {
        const __hip_bfloat16* bs = bsrc0 + b * 32;
        async16(bs,             &B_s[b][tid * 8]);
        async16(bs + 128 * CIN, &B_s[b][(512 + tid) * 8]);
    }
    asm volatile("s_waitcnt vmcnt(2)" ::: "memory");   // A + B0 landed, B1 in flight

    // fragment-read constants
    int ohc = wm >> 6;                    // output h-row block: 0 or 2
    int pbB = lu ^ ((l15 >> 1) & 3);      // B phys chunk (ni-independent)

    float4v acc[8][4] = {};

    #pragma unroll 3
    for (int kt = 0; kt < 36; ++kt) {
        BAR();                            // publishes B(kt) (drained last iter)

        if (kt < 34) {                    // stage B(kt+2) into buf (kt+2)%3
            int t2 = kt + 2, tap2 = t2 >> 2, kb2 = t2 & 3;
            const __hip_bfloat16* bs = bsrc0 + (size_t)tap2 * (COUT * CIN) + kb2 * 32;
            short* Bd = &B_s[(kt + 2) % 3][0];       // compile-time under unroll 3
            async16(bs,             Bd + tid * 8);
            async16(bs + 128 * CIN, Bd + (512 + tid) * 8);
        }

        // ---- compute tile kt: tap = kt>>2, kb = kt&3
        int tap = kt >> 2, kb = kt & 3;
        int kh  = (tap * 11) >> 5, kw = tap - kh * 3;
        int rb0 = (ohc + kh) * 66 + l15 + kw;        // A row base (mi>>2 == 0)
        int cL  = kb * 4 + lu;                       // logical A chunk
        int c7  = cL & 7, cg = cL & 8;
        const short* Bb = &B_s[kt % 3][0];

        short8 aF[8], bF[4];
        #pragma unroll
        for (int mi = 0; mi < 8; ++mi) {
            int r    = rb0 + (mi >> 2) * 66 + (mi & 3) * 16;
            int phys = (c7 ^ (r & 7)) | cg;
            aF[mi] = *(const short8*)&A_s[r * 128 + phys * 8];
        }
        #pragma unroll
        for (int ni = 0; ni < 4; ++ni) {
            int co = wn + ni * 16 + l15;
            bF[ni] = *(const short8*)&Bb[co * 32 + pbB * 8];
        }

        SETPRIO(1);
        #pragma unroll
        for (int mi = 0; mi < 8; ++mi)
            #pragma unroll
            for (int ni = 0; ni < 4; ++ni)
                acc[mi][ni] = __builtin_amdgcn_mfma_f32_16x16x32_bf16(
                    aF[mi], bF[ni], acc[mi][ni], 0, 0, 0);
        SETPRIO(0);

        if (kt < 34) asm volatile("s_waitcnt vmcnt(2)" ::: "memory");
        else         asm volatile("s_waitcnt vmcnt(0)" ::: "memory");
    }

    // epilogue: += ctx, write float4 (4 consecutive w)
    #pragma unroll
    for (int ni = 0; ni < 4; ++ni) {
        int co = wn + ni * 16 + l15;
        float cv = ctx[n * COUT + co];
        float* ob = out + ((size_t)n * COUT + co) * (HH * WW);
        #pragma unroll
        for (int mi = 0; mi < 8; ++mi) {
            int rp = wm + mi * 16 + (lu << 2);       // row quad base
            int hh = h0 + (rp >> 6);
            int ww = rp & 63;
            float4v v = acc[mi][ni] + cv;
            *(float4v*)&ob[hh * WW + ww] = v;
        }
    }
}

// ---------------- fallback (round-2 verified) ----------------------------------
__global__ __launch_bounds__(256) void contextual_conv_f32(
    const float* __restrict__ x, const float* __restrict__ c,
    const float* __restrict__ wgt, const float* __restrict__ cw,
    const float* __restrict__ bias, float* __restrict__ out)
{
    int idx = blockIdx.x * 256 + threadIdx.x;
    int w = idx & 63, h = (idx >> 6) & 63, cb = (idx >> 12) & 63, n = idx >> 18;
    float acc[4];
    #pragma unroll
    for (int j = 0; j < 4; ++j) acc[j] = bias[cb + j * 64];
    const float* cp = c + n * CDIM;
    for (int d = 0; d < CDIM; ++d) {
        float cv = cp[d];
        #pragma unroll
        for (int j = 0; j < 4; ++j) acc[j] += cv * cw[(cb + j * 64) * CDIM + d];
    }
    const float* xn = x + (size_t)n * (CIN * HH * WW);
    for (int ci = 0; ci < CIN; ++ci) {
        const float* xc = xn + ci * (HH * WW);
        float wv[4][9];
        #pragma unroll
        for (int j = 0; j < 4; ++j) {
            const float* wp = wgt + ((cb + j * 64) * CIN + ci) * 9;
            #pragma unroll
            for (int k = 0; k < 9; ++k) wv[j][k] = wp[k];
        }
        #pragma unroll
        for (int kh = 0; kh < 3; ++kh) {
            int hh = h + kh - 1;
            if (hh < 0 || hh >= HH) continue;
            const float* xr = xc + hh * WW;
            #pragma unroll
            for (int kw = 0; kw < 3; ++kw) {
                int ww = w + kw - 1;
                if (ww < 0 || ww >= WW) continue;
                float xv = xr[ww];
                #pragma unroll
                for (int j = 0; j < 4; ++j) acc[j] += xv * wv[j][kh * 3 + kw];
            }
        }
    }
    size_t obase = (size_t)n * (COUT * HH * WW) + (size_t)h * WW + w;
    #pragma unroll
    for (int j = 0; j < 4; ++j)
        out[obase + (size_t)(cb + j * 64) * (HH * WW)] = acc[j];
}

extern "C" void kernel_launch(void* const* d_in, const int* in_sizes, int n_in,
                              void* d_out, int out_size, void* d_ws, size_t ws_size,
                              hipStream_t stream) {
    const float* x    = (const float*)d_in[0];
    const float* c    = (const float*)d_in[1];
    const float* wgt  = (const float*)d_in[2];
    const float* cw   = (const float*)d_in[3];
    const float* bias = (const float*)d_in[4];
    float* out = (float*)d_out;

    if (ws_size < WS_NEEDED) {   // workspace too small: round-2 fallback
        const int total_threads = NN * 64 * HH * WW;
        contextual_conv_f32<<<total_threads / 256, 256, 0, stream>>>(x, c, wgt, cw, bias, out);
        return;
    }

    char* ws = (char*)d_ws;
    __hip_bfloat16* xP = (__hip_bfloat16*)ws;
    __hip_bfloat16* wT = (__hip_bfloat16*)(ws + XP_BYTES);
    float*          cx = (float*)(ws + XP_BYTES + WT_BYTES);

    prep_all <<<3752, 256, 0, stream>>>(x, c, wgt, cw, bias, xP, wT, cx);
    conv_mfma<<<512, 512, 0, stream>>>(xP, wT, cx, out);
}